// Round 5
// baseline (121.601 us; speedup 1.0000x reference)
//
#include <hip/hip_runtime.h>

#define R_   1024
#define B_   4
#define C_   256
#define H_   64
#define W_   64
#define PHW_ 49
#define GREC 16    // f32 dwords per bin geometry record
#define CL_  128   // channels per main block (half of C_)
#define LROW 130   // staging row floats (128 + 2 pad)

__device__ __forceinline__ void cell_w(float start, float end, float s, float& g0, float& g1) {
    float y0 = fmaxf(start, s);
    float yl = fmaxf(fminf(end, s + 1.0f), y0);
    float a  = y0 - s;
    float la = yl - s;
    g0 = la - 0.5f * la * la - a + 0.5f * a * a;
    g1 = 0.5f * la * la - 0.5f * a * a;
}

// ---- prep: transpose (B,C,H,W)->(B,H*W,C)  +  deterministic ROI sort (block x==128) ----
__global__ __launch_bounds__(256) void prep(const float* __restrict__ in,
                                            float* __restrict__ outT,
                                            const float* __restrict__ rois,
                                            int* __restrict__ perm) {
    if (blockIdx.x == 128) {
        if (blockIdx.y | blockIdx.z) return;
        if (threadIdx.x >= 64) return;
        // 1 wave: ballot-based stable counting sort by (batch, y-band). Deterministic.
        int lane = threadIdx.x;
        unsigned long long below = (1ull << lane) - 1ull;
        int key[16];
#pragma unroll
        for (int i = 0; i < 16; ++i) {
            int idx = i * 64 + lane;
            const float* roi = rois + idx * 5;
            int b = (int)roi[0];
            float yc = (roi[2] + roi[4]) * 0.5f * 0.0625f;
            int yb = min(3, max(0, (int)(yc * 0.0625f)));
            key[i] = b * 4 + yb;
        }
        int cnt[16];
#pragma unroll
        for (int k = 0; k < 16; ++k) cnt[k] = 0;
        for (int i = 0; i < 16; ++i)
#pragma unroll
            for (int k = 0; k < 16; ++k)
                cnt[k] += __popcll(__ballot(key[i] == k));
        int off[16]; int acc = 0;
#pragma unroll
        for (int k = 0; k < 16; ++k) { off[k] = acc; acc += cnt[k]; }
        for (int i = 0; i < 16; ++i) {
#pragma unroll
            for (int k = 0; k < 16; ++k) {
                unsigned long long m = __ballot(key[i] == k);
                if (key[i] == k)
                    perm[off[k] + __popcll(m & below)] = i * 64 + lane;
                off[k] += __popcll(m);
            }
        }
        return;
    }

    __shared__ float tile[32][33];
    int b  = blockIdx.z;
    int c0 = blockIdx.y * 32;
    int p0 = blockIdx.x * 32;
    int tx = threadIdx.x & 31;
    int ty = threadIdx.x >> 5;   // 0..7
    const float* src = in + (size_t)b * C_ * (H_ * W_);
#pragma unroll
    for (int i = 0; i < 32; i += 8)
        tile[ty + i][tx] = src[(size_t)(c0 + ty + i) * (H_ * W_) + (p0 + tx)];
    __syncthreads();
    float* dst = outT + (size_t)b * (H_ * W_) * C_;
#pragma unroll
    for (int i = 0; i < 32; i += 8)
        dst[(size_t)(p0 + ty + i) * C_ + (c0 + tx)] = tile[tx][ty + i];
}

// ---- main: 2 blocks per ROI (half channels each); in-LDS geometry; f32 LDS staging ----
__global__ __launch_bounds__(512) void prroi_main(const float* __restrict__ fT,
                                                  const float* __restrict__ rois,
                                                  const int* __restrict__ perm,
                                                  float* __restrict__ out) {
    __shared__ float gsh[PHW_ * GREC];            //  3,136 B
    __shared__ __align__(16) float st[PHW_ * LROW]; // 25,480 B
    int bid  = blockIdx.x;
    // XCD-aware chunking over sorted order; both halves of an ROI on the same XCD.
    int spos = ((bid & 7) << 8) | (bid >> 3);
    int sr   = spos >> 1;
    int half = spos & 1;
    int r    = __builtin_amdgcn_readfirstlane(perm[sr]);
    int tid  = threadIdx.x;

    // ---- phase 0: geometry for all 49 bins, once per block ----
    if (tid < PHW_) {
        int ph = tid / 7, pw = tid - ph * 7;
        const float* roi = rois + r * 5;
        int bb = (int)roi[0];
        float x1 = roi[1] * 0.0625f, y1 = roi[2] * 0.0625f;
        float x2 = roi[3] * 0.0625f, y2 = roi[4] * 0.0625f;
        float rw = fmaxf(x2 - x1, 0.0f), rh = fmaxf(y2 - y1, 0.0f);
        float bw = rw / 7.0f, bh = rh / 7.0f;
        float win = bw * bh;
        float rec[GREC];
#pragma unroll
        for (int t = 0; t < GREC; ++t) rec[t] = 0.0f;
        if (win > 0.0f) {
            float ws = x1 + bw * (float)pw, we = ws + bw;
            float hs = y1 + bh * (float)ph, he = hs + bh;
            float s0w = floorf(ws), s0h = floorf(hs);
            int w0 = (int)s0w, h0 = (int)s0h;   // >= 0 for this input range
            float wy[7], wx[7];
#pragma unroll
            for (int t = 0; t < 7; ++t) { wy[t] = 0.0f; wx[t] = 0.0f; }
#pragma unroll
            for (int o = 0; o < 6; ++o) {
                float g0, g1;
                cell_w(hs, he, s0h + (float)o, g0, g1);
                wy[o] += g0; wy[o + 1] += g1;
                cell_w(ws, we, s0w + (float)o, g0, g1);
                wx[o] += g0; wx[o + 1] += g1;
            }
            int npy = min(7, max(0, (int)ceilf(he - s0h + 1.0f)));
            int npx = min(7, max(0, (int)ceilf(we - s0w + 1.0f)));
            npy = max(0, min(npy, H_ - h0));
            npx = max(0, min(npx, W_ - w0));
            float invwin = 1.0f / win;
#pragma unroll
            for (int t = 0; t < 7; ++t) { rec[t] = wy[t] * invwin; rec[7 + t] = wx[t]; }
            rec[14] = __int_as_float(h0 | (w0 << 8) | (npy << 16) | (npx << 24));
        }
        rec[15] = __int_as_float(bb);
        float4* gp = (float4*)&gsh[tid * GREC];
        gp[0] = make_float4(rec[0],  rec[1],  rec[2],  rec[3]);
        gp[1] = make_float4(rec[4],  rec[5],  rec[6],  rec[7]);
        gp[2] = make_float4(rec[8],  rec[9],  rec[10], rec[11]);
        gp[3] = make_float4(rec[12], rec[13], rec[14], rec[15]);
    }
    __syncthreads();

    int wid  = tid >> 6;
    int lane = tid & 63;
    int c0   = half * CL_ + lane * 2;
    int bb   = __float_as_int(gsh[15]);
    const float* fb = fT + (size_t)bb * (H_ * W_ * C_) + c0;

    // ---- phase 1: gather + separable accumulate (float2 per lane) ----
    for (int k = wid; k < PHW_; k += 8) {
        const float4* g = (const float4*)&gsh[k * GREC];
        float4 q0 = g[0], q1 = g[1], q2 = g[2], q3 = g[3];
        float wy[7] = {q0.x, q0.y, q0.z, q0.w, q1.x, q1.y, q1.z};
        float wx[7] = {q1.w, q2.x, q2.y, q2.z, q2.w, q3.x, q3.y};
        int pk  = __float_as_int(q3.z);
        int h0  = pk & 0xff;
        int w0  = (pk >> 8)  & 0xff;
        int npy = (pk >> 16) & 0xff;
        int npx = (pk >> 24) & 0xff;

        const float* fr = fb + (h0 * W_ + w0) * C_;
        float ax = 0.0f, ay = 0.0f;
#pragma unroll
        for (int dy = 0; dy < 7; ++dy) {
            if (dy < npy) {                      // wave-uniform
                const float* rp = fr + dy * (W_ * C_);
                float rx = 0.0f, ry = 0.0f;
#pragma unroll
                for (int dx = 0; dx < 7; ++dx) {
                    if (dx < npx) {              // wave-uniform
                        float2 v = *(const float2*)(rp + dx * C_);
                        float gx = wx[dx];
                        rx = fmaf(gx, v.x, rx);
                        ry = fmaf(gx, v.y, ry);
                    }
                }
                float gy = wy[dy];
                ax = fmaf(gy, rx, ax);
                ay = fmaf(gy, ry, ay);
            }
        }
        *(float2*)&st[k * LROW + lane * 2] = make_float2(ax, ay);
    }
    __syncthreads();

    // ---- phase 2: contiguous 25 KB flush (out[r, half*128 .. , :]) ----
    float* outr = out + (size_t)r * (C_ * PHW_) + (size_t)half * (CL_ * PHW_);
#pragma unroll 4
    for (int j = tid; j < CL_ * PHW_; j += 512) {
        int c = j / PHW_;
        int k = j - c * PHW_;
        outr[j] = st[k * LROW + c];
    }
}

// ---------------- fallback: original (B,C,H,W) layout, no workspace ----------------
__global__ __launch_bounds__(256) void prroi_pool_direct(const float* __restrict__ f,
                                                         const float* __restrict__ rois,
                                                         float* __restrict__ out) {
    int bin = blockIdx.x;
    int r  = bin / PHW_;
    int k  = bin - r * PHW_;
    int ph = k / 7;
    int pw = k - ph * 7;
    int c = threadIdx.x;

    const float* roi = rois + r * 5;
    int bb = (int)roi[0];
    float x1 = roi[1] * 0.0625f, y1 = roi[2] * 0.0625f;
    float x2 = roi[3] * 0.0625f, y2 = roi[4] * 0.0625f;
    float rw = fmaxf(x2 - x1, 0.0f), rh = fmaxf(y2 - y1, 0.0f);
    float bw = rw / 7.0f, bh = rh / 7.0f;
    float win = bw * bh;
    size_t oidx = ((size_t)r * C_ + c) * PHW_ + k;
    if (!(win > 0.0f)) { out[oidx] = 0.0f; return; }

    float ws = x1 + bw * (float)pw, we = ws + bw;
    float hs = y1 + bh * (float)ph, he = hs + bh;
    float s0w = floorf(ws), s0h = floorf(hs);
    int w0 = (int)s0w, h0 = (int)s0h;
    float wy[7], wx[7];
#pragma unroll
    for (int t = 0; t < 7; ++t) { wy[t] = 0.0f; wx[t] = 0.0f; }
#pragma unroll
    for (int o = 0; o < 6; ++o) {
        float g0, g1;
        cell_w(hs, he, s0h + (float)o, g0, g1);
        wy[o] += g0; wy[o + 1] += g1;
        cell_w(ws, we, s0w + (float)o, g0, g1);
        wx[o] += g0; wx[o + 1] += g1;
    }
    int npy = min(7, max(0, (int)ceilf(he - s0h + 1.0f)));
    int npx = min(7, max(0, (int)ceilf(we - s0w + 1.0f)));
    npy = max(0, min(npy, H_ - h0));
    npx = max(0, min(npx, W_ - w0));

    const float* fbc = f + ((size_t)bb * C_ + c) * (H_ * W_);
    float acc = 0.0f;
#pragma unroll
    for (int dy = 0; dy < 7; ++dy) {
        if (dy < npy) {
            float row = 0.0f;
#pragma unroll
            for (int dx = 0; dx < 7; ++dx) {
                if (dx < npx)
                    row = fmaf(wx[dx], fbc[(h0 + dy) * W_ + (w0 + dx)], row);
            }
            acc = fmaf(wy[dy], row, acc);
        }
    }
    out[oidx] = acc / win;
}

extern "C" void kernel_launch(void* const* d_in, const int* in_sizes, int n_in,
                              void* d_out, int out_size, void* d_ws, size_t ws_size,
                              hipStream_t stream) {
    const float* feat = (const float*)d_in[0];
    const float* rois = (const float*)d_in[1];
    float* out = (float*)d_out;

    const size_t feat_bytes = (size_t)B_ * C_ * H_ * W_ * sizeof(float);   // 16,777,216
    const size_t perm_bytes = (size_t)R_ * sizeof(int);                    // 4,096

    if (ws_size >= feat_bytes + perm_bytes) {
        float* fT   = (float*)d_ws;
        int*   perm = (int*)((char*)d_ws + feat_bytes);
        dim3 tg(129, 8, 4);   // x<128: transpose tiles; x==128,y==0,z==0: ROI sort
        prep<<<tg, 256, 0, stream>>>(feat, fT, rois, perm);
        prroi_main<<<2 * R_, 512, 0, stream>>>(fT, rois, perm, out);
    } else {
        prroi_pool_direct<<<R_ * PHW_, 256, 0, stream>>>(feat, rois, out);
    }
}

// Round 6
// 75.667 us; speedup vs baseline: 1.6071x; 1.6071x over previous
//
#include <hip/hip_runtime.h>
#include <hip/hip_fp16.h>

#define R_    1024
#define B_    4
#define C_    256
#define H_    64
#define W_    64
#define PHW_  49
#define GREC  16    // f32 dwords per bin geometry record (64 B)
#define LROWF 258   // fixup LDS row halves (256 + 2 pad)
#define LROW4 260   // mid-tier staging row halves

__device__ __forceinline__ void cell_w(float start, float end, float s, float& g0, float& g1) {
    float y0 = fmaxf(start, s);
    float yl = fmaxf(fminf(end, s + 1.0f), y0);
    float a  = y0 - s;
    float la = yl - s;
    g0 = la - 0.5f * la * la - a + 0.5f * a * a;
    g1 = 0.5f * la * la - 0.5f * a * a;
}

// ---- prep: transpose (B,C,H,W)->(B,H*W,C) [0..4095] + ROI sort [4096] + geometry [4097..4292] ----
__global__ __launch_bounds__(256) void prep(const float* __restrict__ in,
                                            float* __restrict__ outT,
                                            const float* __restrict__ rois,
                                            int* __restrict__ perm,
                                            float* __restrict__ geom) {
    int bid = blockIdx.x;
    if (bid < 4096) {
        __shared__ float tile[32][33];
        int b   = bid >> 10;
        int rem = bid & 1023;
        int c0  = (rem >> 7) * 32;
        int p0  = (rem & 127) * 32;
        int tx  = threadIdx.x & 31;
        int ty  = threadIdx.x >> 5;
        const float* src = in + (size_t)b * C_ * (H_ * W_);
#pragma unroll
        for (int i = 0; i < 32; i += 8)
            tile[ty + i][tx] = src[(size_t)(c0 + ty + i) * (H_ * W_) + (p0 + tx)];
        __syncthreads();
        float* dst = outT + (size_t)b * (H_ * W_) * C_;
#pragma unroll
        for (int i = 0; i < 32; i += 8)
            dst[(size_t)(p0 + ty + i) * C_ + (c0 + tx)] = tile[tx][ty + i];
        return;
    }
    if (bid == 4096) {
        if (threadIdx.x >= 64) return;
        // 1 wave: ballot-based stable counting sort by (batch, y-band). Deterministic.
        int lane = threadIdx.x;
        unsigned long long below = (1ull << lane) - 1ull;
        int key[16];
#pragma unroll
        for (int i = 0; i < 16; ++i) {
            int idx = i * 64 + lane;
            const float* roi = rois + idx * 5;
            int b = (int)roi[0];
            float yc = (roi[2] + roi[4]) * 0.5f * 0.0625f;
            int yb = min(3, max(0, (int)(yc * 0.0625f)));
            key[i] = b * 4 + yb;
        }
        int cnt[16];
#pragma unroll
        for (int k = 0; k < 16; ++k) cnt[k] = 0;
        for (int i = 0; i < 16; ++i)
#pragma unroll
            for (int k = 0; k < 16; ++k)
                cnt[k] += __popcll(__ballot(key[i] == k));
        int off[16]; int acc = 0;
#pragma unroll
        for (int k = 0; k < 16; ++k) { off[k] = acc; acc += cnt[k]; }
        for (int i = 0; i < 16; ++i) {
#pragma unroll
            for (int k = 0; k < 16; ++k) {
                unsigned long long m = __ballot(key[i] == k);
                if (key[i] == k)
                    perm[off[k] + __popcll(m & below)] = i * 64 + lane;
                off[k] += __popcll(m);
            }
        }
        return;
    }
    // geometry records
    int i = (bid - 4097) * 256 + threadIdx.x;   // 0..50175 exactly
    int r  = i / PHW_;
    int k  = i - r * PHW_;
    int ph = k / 7, pw = k - ph * 7;
    const float* roi = rois + r * 5;
    int bb = (int)roi[0];
    float x1 = roi[1] * 0.0625f, y1 = roi[2] * 0.0625f;
    float x2 = roi[3] * 0.0625f, y2 = roi[4] * 0.0625f;
    float rw = fmaxf(x2 - x1, 0.0f), rh = fmaxf(y2 - y1, 0.0f);
    float bw = rw / 7.0f, bh = rh / 7.0f;
    float win = bw * bh;
    float rec[GREC];
#pragma unroll
    for (int t = 0; t < GREC; ++t) rec[t] = 0.0f;
    if (win > 0.0f) {
        float ws = x1 + bw * (float)pw, we = ws + bw;
        float hs = y1 + bh * (float)ph, he = hs + bh;
        float s0w = floorf(ws), s0h = floorf(hs);
        int w0 = (int)s0w, h0 = (int)s0h;   // >= 0 for this input range
        float wy[7], wx[7];
#pragma unroll
        for (int t = 0; t < 7; ++t) { wy[t] = 0.0f; wx[t] = 0.0f; }
#pragma unroll
        for (int o = 0; o < 6; ++o) {
            float g0, g1;
            cell_w(hs, he, s0h + (float)o, g0, g1);
            wy[o] += g0; wy[o + 1] += g1;
            cell_w(ws, we, s0w + (float)o, g0, g1);
            wx[o] += g0; wx[o + 1] += g1;
        }
        int npy = min(7, max(0, (int)ceilf(he - s0h + 1.0f)));
        int npx = min(7, max(0, (int)ceilf(we - s0w + 1.0f)));
        npy = max(0, min(npy, H_ - h0));
        npx = max(0, min(npx, W_ - w0));
        float invwin = 1.0f / win;
#pragma unroll
        for (int t = 0; t < 7; ++t) { rec[t] = wy[t] * invwin; rec[7 + t] = wx[t]; }
        rec[14] = __int_as_float(h0 | (w0 << 8) | (npy << 16) | (npx << 24));
    }
    rec[15] = __int_as_float(bb);
    float4* gp = (float4*)(geom + (size_t)i * GREC);
    gp[0] = make_float4(rec[0],  rec[1],  rec[2],  rec[3]);
    gp[1] = make_float4(rec[4],  rec[5],  rec[6],  rec[7]);
    gp[2] = make_float4(rec[8],  rec[9],  rec[10], rec[11]);
    gp[3] = make_float4(rec[12], rec[13], rec[14], rec[15]);
}

// ---- compute: one wave per bin, no LDS, float4 gathers, f16 scratch [r][k][c] ----
__global__ __launch_bounds__(512) void prroi_bins(const float* __restrict__ fT,
                                                  const int* __restrict__ perm,
                                                  const float* __restrict__ geom,
                                                  __half* __restrict__ scr) {
    int bid  = blockIdx.x;                       // 6272 blocks
    int spos = (bid & 7) * 784 + (bid >> 3);     // XCD x owns sorted-bin chunk [x*6272, ...)
    int wid  = threadIdx.x >> 6;
    int lane = threadIdx.x & 63;
    int bin  = __builtin_amdgcn_readfirstlane(spos * 8 + wid);   // sorted bin id, wave-uniform SGPR
    int rs   = bin / PHW_;
    int k    = bin - rs * PHW_;
    int r    = __builtin_amdgcn_readfirstlane(perm[rs]);

    const float4* g = (const float4*)(geom + ((size_t)r * PHW_ + k) * GREC);
    float4 q0 = g[0], q1 = g[1], q2 = g[2], q3 = g[3];
    float wy[7] = {q0.x, q0.y, q0.z, q0.w, q1.x, q1.y, q1.z};
    float wx[7] = {q1.w, q2.x, q2.y, q2.z, q2.w, q3.x, q3.y};
    int pk  = __float_as_int(q3.z);
    int h0  = pk & 0xff;
    int w0  = (pk >> 8)  & 0xff;
    int npy = (pk >> 16) & 0xff;
    int npx = (pk >> 24) & 0xff;
    int bb  = __float_as_int(q3.w);

    const float* fr = fT + (((size_t)bb * (H_ * W_) + (h0 * W_ + w0)) * C_) + lane * 4;
    float ax = 0.0f, ay = 0.0f, az = 0.0f, aw = 0.0f;
#pragma unroll
    for (int dy = 0; dy < 7; ++dy) {
        if (dy < npy) {                          // wave-uniform (SGPR compare)
            const float* rp = fr + dy * (W_ * C_);
            float rx = 0.0f, ry = 0.0f, rz = 0.0f, rw = 0.0f;
#pragma unroll
            for (int dx = 0; dx < 7; ++dx) {
                if (dx < npx) {                  // wave-uniform
                    float4 v = *(const float4*)(rp + dx * C_);
                    float gx = wx[dx];
                    rx = fmaf(gx, v.x, rx);
                    ry = fmaf(gx, v.y, ry);
                    rz = fmaf(gx, v.z, rz);
                    rw = fmaf(gx, v.w, rw);
                }
            }
            float gy = wy[dy];
            ax = fmaf(gy, rx, ax);
            ay = fmaf(gy, ry, ay);
            az = fmaf(gy, rz, az);
            aw = fmaf(gy, rw, aw);
        }
    }
    __half2 lo = __floats2half2_rn(ax, ay);
    __half2 hi = __floats2half2_rn(az, aw);
    __half2* d = (__half2*)(scr + ((size_t)r * PHW_ + k) * C_ + lane * 4);  // 8B-aligned
    d[0] = lo;
    d[1] = hi;
}

// ---- fixup: per-ROI [k][c] f16 -> [c][k] f32 through padded LDS ----
__global__ __launch_bounds__(256) void fixup(const __half* __restrict__ scr,
                                             float* __restrict__ out) {
    __shared__ __align__(4) __half lds_h[PHW_ * LROWF];   // 25,284 B
    int r = blockIdx.x;
    const unsigned int* src = (const unsigned int*)(scr + (size_t)r * PHW_ * C_);  // 49*128 u32
    for (int j = threadIdx.x; j < PHW_ * (C_ / 2); j += 256) {
        int row = j >> 7;          // k
        int col = j & 127;         // c/2
        *(unsigned int*)&lds_h[row * LROWF + col * 2] = src[j];
    }
    __syncthreads();
    float* outr = out + (size_t)r * (C_ * PHW_);
#pragma unroll 4
    for (int j = threadIdx.x; j < C_ * PHW_; j += 256) {
        int c = j / PHW_;
        int k = j - c * PHW_;
        outr[j] = __half2float(lds_h[k * LROWF + c]);
    }
}

// ---- mid-tier (smaller ws): round-4 proven kernel — 1 ROI/block, f16 LDS staging ----
__global__ __launch_bounds__(512) void prroi_pool_roi(const float* __restrict__ fT,
                                                      const int* __restrict__ perm,
                                                      const float* __restrict__ geom,
                                                      float* __restrict__ out) {
    __shared__ __align__(16) unsigned short lds_h[PHW_ * LROW4];
    int bid  = blockIdx.x;
    int spos = ((bid & 7) << 7) | (bid >> 3);
    int r    = __builtin_amdgcn_readfirstlane(perm[spos]);
    int wid  = threadIdx.x >> 6;
    int lane = threadIdx.x & 63;
    int c0   = lane * 4;

    const float* grec0 = geom + (size_t)r * PHW_ * GREC;
    int bb = __float_as_int(grec0[15]);
    const float* fb = fT + (size_t)bb * (H_ * W_ * C_) + c0;

    for (int k = wid; k < PHW_; k += 8) {
        const float* g = grec0 + k * GREC;
        float4 q0 = *(const float4*)(g);
        float4 q1 = *(const float4*)(g + 4);
        float4 q2 = *(const float4*)(g + 8);
        float4 q3 = *(const float4*)(g + 12);
        float wy[7] = {q0.x, q0.y, q0.z, q0.w, q1.x, q1.y, q1.z};
        float wx[7] = {q1.w, q2.x, q2.y, q2.z, q2.w, q3.x, q3.y};
        int pk  = __float_as_int(q3.z);
        int h0  = pk & 0xff;
        int w0  = (pk >> 8)  & 0xff;
        int npy = (pk >> 16) & 0xff;
        int npx = (pk >> 24) & 0xff;

        const float* fr = fb + (h0 * W_ + w0) * C_;
        float ax = 0.0f, ay = 0.0f, az = 0.0f, aw = 0.0f;
#pragma unroll
        for (int dy = 0; dy < 7; ++dy) {
            if (dy < npy) {
                const float* rp = fr + dy * (W_ * C_);
                float rx = 0.0f, ry = 0.0f, rz = 0.0f, rw = 0.0f;
#pragma unroll
                for (int dx = 0; dx < 7; ++dx) {
                    if (dx < npx) {
                        float4 v = *(const float4*)(rp + dx * C_);
                        float gx = wx[dx];
                        rx = fmaf(gx, v.x, rx);
                        ry = fmaf(gx, v.y, ry);
                        rz = fmaf(gx, v.z, rz);
                        rw = fmaf(gx, v.w, rw);
                    }
                }
                float gy = wy[dy];
                ax = fmaf(gy, rx, ax);
                ay = fmaf(gy, ry, ay);
                az = fmaf(gy, rz, az);
                aw = fmaf(gy, rw, aw);
            }
        }
        __half2 lo = __floats2half2_rn(ax, ay);
        __half2 hi = __floats2half2_rn(az, aw);
        __half2* dst = (__half2*)&lds_h[k * LROW4 + c0];
        dst[0] = lo;
        dst[1] = hi;
    }
    __syncthreads();

    float* outr = out + (size_t)r * (C_ * PHW_);
    const __half* lh = (const __half*)lds_h;
#pragma unroll 4
    for (int j = threadIdx.x; j < C_ * PHW_; j += 512) {
        int c = j / PHW_;
        int k = j - c * PHW_;
        outr[j] = __half2float(lh[k * LROW4 + c]);
    }
}

// ---- fallback: original layout, no workspace ----
__global__ __launch_bounds__(256) void prroi_pool_direct(const float* __restrict__ f,
                                                         const float* __restrict__ rois,
                                                         float* __restrict__ out) {
    int bin = blockIdx.x;
    int r  = bin / PHW_;
    int k  = bin - r * PHW_;
    int ph = k / 7;
    int pw = k - ph * 7;
    int c = threadIdx.x;

    const float* roi = rois + r * 5;
    int bb = (int)roi[0];
    float x1 = roi[1] * 0.0625f, y1 = roi[2] * 0.0625f;
    float x2 = roi[3] * 0.0625f, y2 = roi[4] * 0.0625f;
    float rw = fmaxf(x2 - x1, 0.0f), rh = fmaxf(y2 - y1, 0.0f);
    float bw = rw / 7.0f, bh = rh / 7.0f;
    float win = bw * bh;
    size_t oidx = ((size_t)r * C_ + c) * PHW_ + k;
    if (!(win > 0.0f)) { out[oidx] = 0.0f; return; }

    float ws = x1 + bw * (float)pw, we = ws + bw;
    float hs = y1 + bh * (float)ph, he = hs + bh;
    float s0w = floorf(ws), s0h = floorf(hs);
    int w0 = (int)s0w, h0 = (int)s0h;
    float wy[7], wx[7];
#pragma unroll
    for (int t = 0; t < 7; ++t) { wy[t] = 0.0f; wx[t] = 0.0f; }
#pragma unroll
    for (int o = 0; o < 6; ++o) {
        float g0, g1;
        cell_w(hs, he, s0h + (float)o, g0, g1);
        wy[o] += g0; wy[o + 1] += g1;
        cell_w(ws, we, s0w + (float)o, g0, g1);
        wx[o] += g0; wx[o + 1] += g1;
    }
    int npy = min(7, max(0, (int)ceilf(he - s0h + 1.0f)));
    int npx = min(7, max(0, (int)ceilf(we - s0w + 1.0f)));
    npy = max(0, min(npy, H_ - h0));
    npx = max(0, min(npx, W_ - w0));

    const float* fbc = f + ((size_t)bb * C_ + c) * (H_ * W_);
    float acc = 0.0f;
#pragma unroll
    for (int dy = 0; dy < 7; ++dy) {
        if (dy < npy) {
            float row = 0.0f;
#pragma unroll
            for (int dx = 0; dx < 7; ++dx) {
                if (dx < npx)
                    row = fmaf(wx[dx], fbc[(h0 + dy) * W_ + (w0 + dx)], row);
            }
            acc = fmaf(wy[dy], row, acc);
        }
    }
    out[oidx] = acc / win;
}

extern "C" void kernel_launch(void* const* d_in, const int* in_sizes, int n_in,
                              void* d_out, int out_size, void* d_ws, size_t ws_size,
                              hipStream_t stream) {
    const float* feat = (const float*)d_in[0];
    const float* rois = (const float*)d_in[1];
    float* out = (float*)d_out;

    const size_t feat_b = (size_t)B_ * C_ * H_ * W_ * sizeof(float);         // 16,777,216
    const size_t perm_b = (size_t)R_ * sizeof(int);                          //      4,096
    const size_t geom_b = (size_t)R_ * PHW_ * GREC * sizeof(float);          //  3,211,264
    const size_t scr_b  = (size_t)R_ * PHW_ * C_ * sizeof(__half);           // 25,690,112

    if (ws_size >= feat_b + perm_b + geom_b + scr_b) {
        float*  fT   = (float*)d_ws;
        int*    perm = (int*)((char*)d_ws + feat_b);
        float*  geom = (float*)((char*)d_ws + feat_b + perm_b);
        __half* scr  = (__half*)((char*)d_ws + feat_b + perm_b + geom_b);
        prep<<<4293, 256, 0, stream>>>(feat, fT, rois, perm, geom);
        prroi_bins<<<(R_ * PHW_) / 8, 512, 0, stream>>>(fT, perm, geom, scr);
        fixup<<<R_, 256, 0, stream>>>(scr, out);
    } else if (ws_size >= feat_b + perm_b + geom_b) {
        float* fT   = (float*)d_ws;
        int*   perm = (int*)((char*)d_ws + feat_b);
        float* geom = (float*)((char*)d_ws + feat_b + perm_b);
        prep<<<4293, 256, 0, stream>>>(feat, fT, rois, perm, geom);
        prroi_pool_roi<<<R_, 512, 0, stream>>>(fT, perm, geom, out);
    } else {
        prroi_pool_direct<<<R_ * PHW_, 256, 0, stream>>>(feat, rois, out);
    }
}